// Round 10
// baseline (2933.246 us; speedup 1.0000x reference)
//
#include <hip/hip_runtime.h>

#define H_ 96
#define W_ 96
#define NV (H_ * W_)              // 9216
#define SORT_N 16384
#define NT 1024
#define NBANDS 16
#define BROWS (H_ / NBANDS)       // 6
#define BVERTS (BROWS * W_)       // 576
#define DCAP 288                  // deferred/band <= births-1 <= 287
#define NCUTS (NBANDS - 1)        // 15
#define NBE (NCUTS * W_)          // 1440
#define EV_MAX 8192

// LDS ~141 KB (<160 KiB). Lifetime-overlapped regions documented inline.
struct SMem {
  unsigned int   K[SORT_N];        // sortable keys by rank; tail [NV..) reused as dfr
  unsigned short P[SORT_N];        // rank->vid; tail = anchors; head reused as evAB (u32)
  unsigned short parL[NV];         // band UF (vid-indexed); reused as parG (rank-indexed)
  unsigned short BL[NV];           // band lists; reused as evR (u16[8192])
  unsigned short rkB[NCUTS * 192]; // boundary-row vid->rank (per cut: 96 upper, 96 lower)
  double bandT[NBANDS], bandS[NBANDS];
  unsigned int dcnt[NBANDS];
  unsigned int evCount, evM;
};

__device__ __forceinline__ float keyToFloat(unsigned int k) {
  return __uint_as_float((k & 0x80000000u) ? (k ^ 0x80000000u) : ~k);
}

__global__ __launch_bounds__(NT, 1)
void topo_entropy_kernel(const float* __restrict__ x, float* __restrict__ out) {
  __shared__ SMem sm;
  const int tid = threadIdx.x;
  const float* img = x + (size_t)blockIdx.x * NV;

  unsigned short* dfr     = (unsigned short*)&sm.K[NV];  // 16*288*3 u16 = 27648 B (K tail = 28672 B)
  unsigned short* anchors = &sm.P[NV];                   // 2880 u16
  unsigned short* evR     = sm.BL;                       // u16[8192]
  unsigned int*   evAB    = (unsigned int*)sm.P;         // u32[8192]

  // ---- P1: load, order-preserving u32 keys ----
  for (int i = tid; i < SORT_N; i += NT) {
    if (i < NV) {
      unsigned int b = __float_as_uint(img[i]);
      sm.K[i] = b ^ ((b & 0x80000000u) ? 0xFFFFFFFFu : 0x80000000u);
      sm.P[i] = (unsigned short)i;
    } else { sm.K[i] = 0xFFFFFFFFu; sm.P[i] = 0xFFFFu; }
  }
  if (tid < NBANDS) { sm.dcnt[tid] = 0u; sm.bandT[tid] = 0.0; sm.bandS[tid] = 0.0; }
  __syncthreads();

  // ---- P2: bitonic sort ascending (K, P) ----
  for (int k = 2; k <= SORT_N; k <<= 1) {
    for (int j = k >> 1; j > 0; j >>= 1) {
      #pragma unroll 4
      for (int p = tid; p < (SORT_N / 2); p += NT) {
        int i = ((p & ~(j - 1)) << 1) | (p & (j - 1));
        int l = i | j;
        unsigned int ki = sm.K[i], kl = sm.K[l];
        unsigned short pi = sm.P[i], pl = sm.P[l];
        bool up = ((i & k) == 0);
        bool sw = up ? (ki > kl) : (ki < kl);
        sm.K[i] = sw ? kl : ki;  sm.K[l] = sw ? ki : kl;
        sm.P[i] = sw ? pl : pi;  sm.P[l] = sw ? pi : pl;
      }
      __syncthreads();
    }
  }

  // ---- P3: parL root-init (rank in entry) + boundary-row rank LUT ----
  for (int t = tid; t < NV; t += NT) {
    const int vid = (int)sm.P[t];
    sm.parL[vid] = (unsigned short)(0x8000u | (unsigned int)t);
    const int r = vid / W_;
    const int c = vid - r * W_;
    if ((r % BROWS) == BROWS - 1 && r < H_ - 1) sm.rkB[(r / BROWS) * 192 + c] = (unsigned short)t;
    if ((r % BROWS) == 0 && r > 0)              sm.rkB[(r / BROWS - 1) * 192 + 96 + c] = (unsigned short)t;
  }
  // ---- P4: per-band rank lists (wave-cooperative compaction) ----
  {
    const int wv = tid >> 6, lane = tid & 63;
    int cnt = 0;
    for (int t0 = 0; t0 < NV; t0 += 64) {
      const int t = t0 + lane;
      const int vid = (int)sm.P[t];
      const bool mine = (vid / BVERTS) == wv;
      const unsigned long long m = __ballot(mine);
      if (mine)
        sm.BL[wv * BVERTS + cnt + __popcll(m & ((1ull << lane) - 1ull))] = (unsigned short)t;
      cnt += (int)__popcll(m);
    }
  }
  __syncthreads();

  // ---- P5: 16 parallel band-local Kruskal (lane 0 of each wave) ----
  if ((tid & 63) == 0) {
    const int b = tid >> 6;
    const int base = b * BVERTS;
    const int rtop = b * BROWS, rbot = rtop + BROWS - 1;
    unsigned short* db = &dfr[b * DCAP * 3];
    double T = 0.0, S = 0.0;
    int dc = 0;
    int t_n = (int)sm.BL[base];
    for (int j = 0; j < BVERTS; ++j) {
      const int t = t_n;
      if (j + 1 < BVERTS) t_n = (int)sm.BL[base + j + 1];
      const int vid = (int)sm.P[t];
      const float vt = keyToFloat(sm.K[t]);
      const int r = vid / W_;
      const int c = vid - r * W_;
      int n0 = (c > 0)      ? vid - 1  : vid;
      int n1 = (c < W_ - 1) ? vid + 1  : vid;
      int n2 = (r > rtop)   ? vid - W_ : vid;
      int n3 = (r < rbot)   ? vid + W_ : vid;
      int x0 = n0, x1 = n1, x2 = n2, x3 = n3;
      unsigned int p0 = sm.parL[x0], p1 = sm.parL[x1], p2 = sm.parL[x2], p3 = sm.parL[x3];
      const unsigned int self = 0x8000u | (unsigned int)t;
      if ((p0 & 0x8000u) && (int)(p0 & 0x3FFFu) > t) { x0 = vid; n0 = vid; p0 = self; }
      if ((p1 & 0x8000u) && (int)(p1 & 0x3FFFu) > t) { x1 = vid; n1 = vid; p1 = self; }
      if ((p2 & 0x8000u) && (int)(p2 & 0x3FFFu) > t) { x2 = vid; n2 = vid; p2 = self; }
      if ((p3 & 0x8000u) && (int)(p3 & 0x3FFFu) > t) { x3 = vid; n3 = vid; p3 = self; }
      while (!((p0 & p1 & p2 & p3) & 0x8000u)) {
        x0 = (p0 & 0x8000u) ? x0 : (int)p0;
        x1 = (p1 & 0x8000u) ? x1 : (int)p1;
        x2 = (p2 & 0x8000u) ? x2 : (int)p2;
        x3 = (p3 & 0x8000u) ? x3 : (int)p3;
        p0 = sm.parL[x0]; p1 = sm.parL[x1]; p2 = sm.parL[x2]; p3 = sm.parL[x3];
      }
      // prefetch all candidate birth keys (4 parallel LDS reads) -> merge phase is LDS-read-free
      const float v0 = keyToFloat(sm.K[(int)(p0 & 0x3FFFu)]);
      const float v1 = keyToFloat(sm.K[(int)(p1 & 0x3FFFu)]);
      const float v2 = keyToFloat(sm.K[(int)(p2 & 0x3FFFu)]);
      const float v3 = keyToFloat(sm.K[(int)(p3 & 0x3FFFu)]);
      int mv = vid, mr = t;
      float mval = vt;
      unsigned int mtaint = ((r == rtop && b > 0) || (r == rbot && b < NBANDS - 1)) ? 1u : 0u;
      int g0 = -1, g1 = -1, g2 = -1;
      #define DO_CHAIN(pc, xc, vc)                                              \
      {                                                                         \
        const int rr = (int)(pc & 0x3FFFu);                                     \
        const unsigned int rt = (pc >> 14) & 1u;                                \
        const int rv = xc;                                                      \
        if (rr <= t && rv != mv && rv != g0 && rv != g1 && rv != g2) {          \
          int yR, yV; unsigned int yT; float ybv;                               \
          if (rr > mr) { yR = rr; yV = rv; yT = rt; ybv = vc; }                 \
          else { yR = mr; yV = mv; yT = mtaint; ybv = mval;                     \
                 mv = rv; mr = rr; mval = vc; }                                 \
          mtaint |= rt;                                                         \
          if (yT) {                                                             \
            db[dc * 3 + 0] = (unsigned short)t;                                 \
            db[dc * 3 + 1] = (unsigned short)yR;                                \
            db[dc * 3 + 2] = (unsigned short)mr;                                \
            ++dc;                                                               \
          } else {                                                              \
            const float pers = vt - ybv;                                        \
            if (pers > 0.0f) { T += (double)pers;                               \
                               S += (double)(pers * logf(pers)); }              \
          }                                                                     \
          sm.parL[yV] = (unsigned short)mv;                                     \
          g2 = g1; g1 = g0; g0 = yV;                                            \
        }                                                                       \
      }
      DO_CHAIN(p0, x0, v0)
      DO_CHAIN(p1, x1, v1)
      DO_CHAIN(p2, x2, v2)
      DO_CHAIN(p3, x3, v3)
      #undef DO_CHAIN
      sm.parL[mv] = (unsigned short)(0x8000u | (mtaint << 14) | (unsigned int)mr);
      if (vid != mv) sm.parL[vid] = (unsigned short)mv;
      if ((int)(p0 & 0x3FFFu) <= t) { if (n0 != mv) sm.parL[n0] = (unsigned short)mv;
                                      if (x0 != mv && x0 != n0) sm.parL[x0] = (unsigned short)mv; }
      if ((int)(p1 & 0x3FFFu) <= t) { if (n1 != mv) sm.parL[n1] = (unsigned short)mv;
                                      if (x1 != mv && x1 != n1) sm.parL[x1] = (unsigned short)mv; }
      if ((int)(p2 & 0x3FFFu) <= t) { if (n2 != mv) sm.parL[n2] = (unsigned short)mv;
                                      if (x2 != mv && x2 != n2) sm.parL[x2] = (unsigned short)mv; }
      if ((int)(p3 & 0x3FFFu) <= t) { if (n3 != mv) sm.parL[n3] = (unsigned short)mv;
                                      if (x3 != mv && x3 != n3) sm.parL[x3] = (unsigned short)mv; }
      if (r == rbot && b < NBANDS - 1) anchors[b * 192 + c] = (unsigned short)mr;
      if (r == rtop && b > 0)          anchors[(b - 1) * 192 + 96 + c] = (unsigned short)mr;
    }
    sm.bandT[b] = T; sm.bandS[b] = S; sm.dcnt[b] = (unsigned int)dc;
  }
  __syncthreads();

  // ---- P6a: boundary events (rank keys via rkB, anchors payload) + parG init ----
  for (int e = tid; e < NBE; e += NT) {
    const int cut = e / W_;
    const int col = e - cut * W_;
    const unsigned short ru = sm.rkB[cut * 192 + col];
    const unsigned short rv = sm.rkB[cut * 192 + 96 + col];
    evR[e] = ru > rv ? ru : rv;
    evAB[e] = ((unsigned int)anchors[cut * 192 + col] << 16) | anchors[cut * 192 + 96 + col];
  }
  for (int r2 = tid; r2 < NV; r2 += NT) sm.parL[r2] = (unsigned short)0x8000u;  // parG
  if (tid == 0) {
    unsigned int c = NBE;
    for (int q = 0; q < NBANDS; ++q) c += sm.dcnt[q];
    sm.evCount = c;
    unsigned int M = 2048;
    while (M < c) M <<= 1;
    sm.evM = M;
  }
  __syncthreads();

  // ---- P6b: compact deferred events + pad ----
  {
    const int cnt = (int)sm.evCount;
    const int M = (int)sm.evM;
    for (int s = tid; s < NBANDS * DCAP; s += NT) {
      const int b2 = s / DCAP;
      const int i2 = s - b2 * DCAP;
      if ((unsigned)i2 < sm.dcnt[b2]) {
        int off = NBE;
        for (int q = 0; q < b2; ++q) off += (int)sm.dcnt[q];
        const unsigned short* e3 = &dfr[(b2 * DCAP + i2) * 3];
        evR[off + i2] = e3[0];
        evAB[off + i2] = ((unsigned int)e3[1] << 16) | e3[2];
      }
    }
    for (int e = cnt + tid; e < M; e += NT) evR[e] = 0xFFFFu;
  }
  __syncthreads();

  // ---- P7: bitonic sort events by rank key (runtime size M) ----
  {
    const int M = (int)sm.evM;
    for (int k = 2; k <= M; k <<= 1) {
      for (int j = k >> 1; j > 0; j >>= 1) {
        for (int p = tid; p < (M >> 1); p += NT) {
          const int i = ((p & ~(j - 1)) << 1) | (p & (j - 1));
          const int l = i | j;
          const unsigned short ki = evR[i], kl = evR[l];
          const unsigned int ai = evAB[i], al = evAB[l];
          const bool up = ((i & k) == 0);
          const bool sw = up ? (ki > kl) : (ki < kl);
          evR[i] = sw ? kl : ki;  evR[l] = sw ? ki : kl;
          evAB[i] = sw ? al : ai; evAB[l] = sw ? ai : al;
        }
        __syncthreads();
      }
    }
  }

  // ---- P8: serial replay, 4-event speculative batches with register fix-ups ----
  if (tid == 0) {
    double T = 0.0, S = 0.0;
    for (int q = 0; q < NBANDS; ++q) { T += sm.bandT[q]; S += sm.bandS[q]; }
    const int cnt = (int)sm.evCount;
    for (int bs = 0; bs < cnt; bs += 4) {
      // load 4 events (padded slots -> no-op events a=b=0; rank 0 is always a root)
      int A0, A1, A2, A3, B0, B1, B2, B3, W0, W1, W2, W3;
      {
        unsigned int ab;
        if (bs + 0 < cnt) { ab = evAB[bs + 0]; A0 = (int)(ab >> 16); B0 = (int)(ab & 0xFFFFu); W0 = (int)evR[bs + 0]; }
        else { A0 = 0; B0 = 0; W0 = 0; }
        if (bs + 1 < cnt) { ab = evAB[bs + 1]; A1 = (int)(ab >> 16); B1 = (int)(ab & 0xFFFFu); W1 = (int)evR[bs + 1]; }
        else { A1 = 0; B1 = 0; W1 = 0; }
        if (bs + 2 < cnt) { ab = evAB[bs + 2]; A2 = (int)(ab >> 16); B2 = (int)(ab & 0xFFFFu); W2 = (int)evR[bs + 2]; }
        else { A2 = 0; B2 = 0; W2 = 0; }
        if (bs + 3 < cnt) { ab = evAB[bs + 3]; A3 = (int)(ab >> 16); B3 = (int)(ab & 0xFFFFu); W3 = (int)evR[bs + 3]; }
        else { A3 = 0; B3 = 0; W3 = 0; }
      }
      const float D0 = keyToFloat(sm.K[W0]);
      const float D1 = keyToFloat(sm.K[W1]);
      const float D2 = keyToFloat(sm.K[W2]);
      const float D3 = keyToFloat(sm.K[W3]);
      // interleaved stale chase of all 8 chains
      int fa0 = A0, fa1 = A1, fa2 = A2, fa3 = A3;
      int fb0 = B0, fb1 = B1, fb2 = B2, fb3 = B3;
      for (;;) {
        const unsigned int ea0 = sm.parL[fa0], ea1 = sm.parL[fa1];
        const unsigned int ea2 = sm.parL[fa2], ea3 = sm.parL[fa3];
        const unsigned int eb0 = sm.parL[fb0], eb1 = sm.parL[fb1];
        const unsigned int eb2 = sm.parL[fb2], eb3 = sm.parL[fb3];
        if ((ea0 & ea1 & ea2 & ea3 & eb0 & eb1 & eb2 & eb3) & 0x8000u) break;
        fa0 = (ea0 & 0x8000u) ? fa0 : (int)ea0;
        fa1 = (ea1 & 0x8000u) ? fa1 : (int)ea1;
        fa2 = (ea2 & 0x8000u) ? fa2 : (int)ea2;
        fa3 = (ea3 & 0x8000u) ? fa3 : (int)ea3;
        fb0 = (eb0 & 0x8000u) ? fb0 : (int)eb0;
        fb1 = (eb1 & 0x8000u) ? fb1 : (int)eb1;
        fb2 = (eb2 & 0x8000u) ? fb2 : (int)eb2;
        fb3 = (eb3 & 0x8000u) ? fb3 : (int)eb3;
      }
      // prefetch birth keys of all stale roots (8 parallel reads)
      const float ka0 = keyToFloat(sm.K[fa0]), kb0 = keyToFloat(sm.K[fb0]);
      const float ka1 = keyToFloat(sm.K[fa1]), kb1 = keyToFloat(sm.K[fb1]);
      const float ka2 = keyToFloat(sm.K[fa2]), kb2 = keyToFloat(sm.K[fb2]);
      const float ka3 = keyToFloat(sm.K[fa3]), kb3 = keyToFloat(sm.K[fb3]);
      // in-order commit with register union-history fix-ups
      int hy0 = -1, hy1 = -1, hy2 = -1, he0 = 0, he1 = 0, he2 = 0, nh = 0;
      #define COMMIT(Aj, Bj, faj, fbj, kaj, kbj, Dj, OKj)                        \
      {                                                                          \
        int fa = faj, fb = fbj;                                                  \
        if (fa == hy0) fa = he0;  if (fa == hy1) fa = he1;  if (fa == hy2) fa = he2; \
        if (fb == hy0) fb = he0;  if (fb == hy1) fb = he1;  if (fb == hy2) fb = he2; \
        if (OKj && fa != fb) {                                                   \
          const int y = fa > fb ? fa : fb;                                       \
          const int el = fa + fb - y;                                            \
          const float by = (y == faj) ? kaj : ((y == fbj) ? kbj                  \
                             : keyToFloat(sm.K[y]));                             \
          const float pers = Dj - by;                                            \
          if (pers > 0.0f) { T += (double)pers;                                  \
                             S += (double)(pers * logf(pers)); }                 \
          sm.parL[y] = (unsigned short)el;                                       \
          if (nh == 0) { hy0 = y; he0 = el; }                                    \
          else if (nh == 1) { hy1 = y; he1 = el; }                               \
          else if (nh == 2) { hy2 = y; he2 = el; }                               \
          ++nh;                                                                  \
          if (Aj != el && Aj != y) sm.parL[Aj] = (unsigned short)el;             \
          if (Bj != el && Bj != y) sm.parL[Bj] = (unsigned short)el;             \
        } else {                                                                 \
          if (Aj != fa) sm.parL[Aj] = (unsigned short)fa;                        \
          if (Bj != fb) sm.parL[Bj] = (unsigned short)fb;                        \
        }                                                                        \
      }
      COMMIT(A0, B0, fa0, fb0, ka0, kb0, D0, (bs + 0 < cnt))
      COMMIT(A1, B1, fa1, fb1, ka1, kb1, D1, (bs + 1 < cnt))
      COMMIT(A2, B2, fa2, fb2, ka2, kb2, D2, (bs + 2 < cnt))
      COMMIT(A3, B3, fa3, fb3, ka3, kb3, D3, (bs + 3 < cnt))
      #undef COMMIT
    }
    out[blockIdx.x] = (T > 0.0) ? (float)(log(T) - S / T) : 0.0f;
  }
}

extern "C" void kernel_launch(void* const* d_in, const int* in_sizes, int n_in,
                              void* d_out, int out_size, void* d_ws, size_t ws_size,
                              hipStream_t stream) {
  (void)d_ws; (void)ws_size; (void)n_in; (void)out_size;
  const float* x = (const float*)d_in[0];
  float* out = (float*)d_out;
  int n_img = in_sizes[0] / NV;   // 64
  if (n_img <= 0) n_img = 1;
  topo_entropy_kernel<<<n_img, NT, 0, stream>>>(x, out);
}